// Round 4
// baseline (212.618 us; speedup 1.0000x reference)
//
#include <hip/hip_runtime.h>
#include <math.h>

#define B_DIM 16
#define C_DIM 256
#define NV    40962
#define K_NEI 7
#define NPAIR (NV / 2)   // 20481

typedef float v2f __attribute__((ext_vector_type(2)));

// Fused pool + transpose with COALESCED writes.
// Block = 256 threads = 16 b  x  16 n-pairs (32 consecutive n).
// Read: lane group (16 lanes, same b) reads contiguous 128B; wave = 4x128B segments.
// After c-loop: transpose 32n x 16b through padded LDS tile, then write poolT's
// contiguous 8KB span ([n][b] layout) with coalesced float4 stores.
__global__ void pool_kernel(const float* __restrict__ x, float2* __restrict__ poolT) {
    int tid = threadIdx.x;
    int b   = tid >> 4;                    // 0..15
    int p   = tid & 15;                    // pair-in-block 0..15
    int pair = blockIdx.x * 16 + p;        // global n-pair
    bool valid = pair < NPAIR;
    int n2 = valid ? pair : NPAIR - 1;     // clamp (tail block); results discarded

    const float* xb = x + (size_t)b * C_DIM * NV + 2 * (size_t)n2;

    float sx = 0.f, sy = 0.f;
    float mx = -INFINITY, my = -INFINITY;
    #pragma unroll 16
    for (int c = 0; c < C_DIM; ++c) {
        v2f v = __builtin_nontemporal_load(
                    reinterpret_cast<const v2f*>(xb + (size_t)c * NV));
        sx += v.x; sy += v.y;
        mx = fmaxf(mx, v.x);
        my = fmaxf(my, v.y);
    }
    const float inv = 1.0f / (float)C_DIM;

    __shared__ float2 tile[32][17];        // +1 pad: write phase 2-way (free)
    tile[2 * p][b]     = make_float2(sx * inv, mx);
    tile[2 * p + 1][b] = make_float2(sy * inv, my);
    __syncthreads();

    int n0 = blockIdx.x * 32;
    int nvalid = NV - n0; if (nvalid > 32) nvalid = 32;
    int nf4 = nvalid * 8;                  // float4s to store (256 normally)
    float4* dst = reinterpret_cast<float4*>(poolT + (size_t)n0 * 16);
    for (int e = tid; e < nf4; e += 256) {
        int nl = e >> 3;                   // local n 0..31
        int bb = (2 * e) & 15;             // even b
        float2 a0 = tile[nl][bb];
        float2 a1 = tile[nl][bb + 1];
        dst[e] = make_float4(a0.x, a0.y, a1.x, a1.y);
    }
}

// att2: one thread per vertex n, all 16 b. Each of the 7 gathers is a full
// 128B line (8x float4, 100% line utilization); idx read once per n; stores
// wave-coalesced per b. Arithmetic order identical to passing version.
__global__ void att2_kernel(const float2* __restrict__ poolT,
                            const int* __restrict__ idx,
                            const float* __restrict__ W,
                            const float* __restrict__ bias,
                            float* __restrict__ out) {
    int n = blockIdx.x * 64 + threadIdx.x;
    if (n >= NV) return;

    float w[2 * K_NEI];
    #pragma unroll
    for (int i = 0; i < 2 * K_NEI; ++i) w[i] = W[i];
    float bb = bias[0];

    float acc[16];
    #pragma unroll
    for (int b = 0; b < 16; ++b) acc[b] = bb;

    #pragma unroll
    for (int k = 0; k < K_NEI; ++k) {
        int j = idx[n * K_NEI + k];
        const float4* L = reinterpret_cast<const float4*>(poolT + (size_t)j * 16);
        #pragma unroll
        for (int q = 0; q < 8; ++q) {
            float4 v = L[q];
            acc[2 * q]     = fmaf(w[2 * k + 1], v.y, fmaf(w[2 * k], v.x, acc[2 * q]));
            acc[2 * q + 1] = fmaf(w[2 * k + 1], v.w, fmaf(w[2 * k], v.z, acc[2 * q + 1]));
        }
    }
    #pragma unroll
    for (int b = 0; b < 16; ++b)
        __builtin_nontemporal_store(1.0f / (1.0f + expf(-acc[b])),
                                    &out[(size_t)b * NV + n]);
}

extern "C" void kernel_launch(void* const* d_in, const int* in_sizes, int n_in,
                              void* d_out, int out_size, void* d_ws, size_t ws_size,
                              hipStream_t stream) {
    const float* x     = (const float*)d_in[0];
    const int*   neigh = (const int*)  d_in[1];
    const float* W     = (const float*)d_in[2];
    const float* bias  = (const float*)d_in[3];
    float*       out   = (float*)d_out;

    float2* poolT = (float2*)d_ws;        // [NV][16] float2 = 5.24 MB

    int nblk = (NPAIR + 15) / 16;         // 1281
    pool_kernel<<<nblk, 256, 0, stream>>>(x, poolT);

    int ntile = (NV + 63) / 64;           // 641
    att2_kernel<<<ntile, 64, 0, stream>>>(poolT, neigh, W, bias, out);
}

// Round 5
// 132.122 us; speedup vs baseline: 1.6093x; 1.6093x over previous
//
#include <hip/hip_runtime.h>
#include <math.h>

#define B_DIM 16
#define C_DIM 256
#define NV    40962
#define K_NEI 7
#define NPAIR (NV / 2)   // 20481

typedef float v2f __attribute__((ext_vector_type(2)));

// Kernel 1 (R2-proven): channel-wise mean+max, thread = (b, n-pair).
// Wave reads 512B contiguous per c; writes [b][n] float2 as coalesced float4.
__global__ void pool_kernel(const float* __restrict__ x, float4* __restrict__ pool) {
    int t = blockIdx.x * blockDim.x + threadIdx.x;
    if (t >= B_DIM * NPAIR) return;
    int b  = t / NPAIR;
    int n2 = t - b * NPAIR;

    const float* xb = x + (size_t)b * C_DIM * NV + 2 * (size_t)n2;

    float sx = 0.f, sy = 0.f;
    float mx = -INFINITY, my = -INFINITY;
    #pragma unroll 16
    for (int c = 0; c < C_DIM; ++c) {
        v2f v = __builtin_nontemporal_load(
                    reinterpret_cast<const v2f*>(xb + (size_t)c * NV));
        sx += v.x; sy += v.y;
        mx = fmaxf(mx, v.x);
        my = fmaxf(my, v.y);
    }
    const float inv = 1.0f / (float)C_DIM;
    float4 o;
    o.x = sx * inv; o.y = mx;
    o.z = sy * inv; o.w = my;
    pool[((size_t)b * NV + 2 * (size_t)n2) >> 1] = o;
}

// Kernel 2 (R2-proven): transpose pool [b][n] -> poolT [n][b].
__global__ void transpose_kernel(const float2* __restrict__ pool,
                                 float2* __restrict__ poolT) {
    __shared__ float2 tile[64][17];
    int n0 = blockIdx.x * 64;
    int i  = threadIdx.x & 63;
    int bq = threadIdx.x >> 6;        // 0..3
    #pragma unroll
    for (int p = 0; p < 4; ++p) {
        int b = p * 4 + bq;
        if (n0 + i < NV)
            tile[i][b] = pool[(size_t)b * NV + n0 + i];
    }
    __syncthreads();
    int valid = NV - n0; if (valid > 64) valid = 64;
    int nf4 = valid * 8;
    float4* dst = reinterpret_cast<float4*>(poolT + (size_t)n0 * 16);
    for (int e = threadIdx.x; e < nf4; e += 256) {
        int e2 = e * 2;
        int n  = e2 >> 4;
        int b  = e2 & 15;
        float2 a0 = tile[n][b];
        float2 a1 = tile[n][b + 1];
        dst[e] = make_float4(a0.x, a0.y, a1.x, a1.y);
    }
}

// Kernel 3 (new): 4 threads per vertex, 4 b each. 4 consecutive lanes fetch
// the 4 quarters of poolT[j]'s 128B line (fully coalesced); 4x the waves of
// the old 1-thread-per-n version (10 waves/CU vs 2.5) to hide gather latency.
// FMA order per (b,n) identical to the passing version.
__global__ void att4_kernel(const float2* __restrict__ poolT,
                            const int* __restrict__ idx,
                            const float* __restrict__ W,
                            const float* __restrict__ bias,
                            float* __restrict__ out) {
    int tid = threadIdx.x;
    int n   = blockIdx.x * 64 + (tid >> 2);
    int bq  = tid & 3;                 // owns b = bq*4 .. bq*4+3
    if (n >= NV) return;

    float w[2 * K_NEI];
    #pragma unroll
    for (int i = 0; i < 2 * K_NEI; ++i) w[i] = W[i];
    float bb = bias[0];

    float acc[4];
    #pragma unroll
    for (int r = 0; r < 4; ++r) acc[r] = bb;

    #pragma unroll
    for (int k = 0; k < K_NEI; ++k) {
        int j = idx[n * K_NEI + k];
        const float4* L = reinterpret_cast<const float4*>(poolT + (size_t)j * 16 + bq * 4);
        float4 v0 = L[0];              // b = bq*4+0, bq*4+1
        float4 v1 = L[1];              // b = bq*4+2, bq*4+3
        acc[0] = fmaf(w[2 * k + 1], v0.y, fmaf(w[2 * k], v0.x, acc[0]));
        acc[1] = fmaf(w[2 * k + 1], v0.w, fmaf(w[2 * k], v0.z, acc[1]));
        acc[2] = fmaf(w[2 * k + 1], v1.y, fmaf(w[2 * k], v1.x, acc[2]));
        acc[3] = fmaf(w[2 * k + 1], v1.w, fmaf(w[2 * k], v1.z, acc[3]));
    }
    #pragma unroll
    for (int r = 0; r < 4; ++r)
        out[(size_t)(bq * 4 + r) * NV + n] = 1.0f / (1.0f + expf(-acc[r]));
}

extern "C" void kernel_launch(void* const* d_in, const int* in_sizes, int n_in,
                              void* d_out, int out_size, void* d_ws, size_t ws_size,
                              hipStream_t stream) {
    const float* x     = (const float*)d_in[0];
    const int*   neigh = (const int*)  d_in[1];
    const float* W     = (const float*)d_in[2];
    const float* bias  = (const float*)d_in[3];
    float*       out   = (float*)d_out;

    const size_t POOL_BYTES = (size_t)B_DIM * NV * sizeof(float2); // 5.24 MB

    float4* pool4 = (float4*)d_ws;                 // [b][n] staging
    float2* poolT = (float2*)((char*)d_ws + POOL_BYTES); // [n][b]

    int t1 = B_DIM * NPAIR;
    pool_kernel<<<(t1 + 255) / 256, 256, 0, stream>>>(x, pool4);

    int ntile = (NV + 63) / 64;       // 641
    transpose_kernel<<<ntile, 256, 0, stream>>>((const float2*)d_ws, poolT);
    att4_kernel<<<ntile, 256, 0, stream>>>(poolT, neigh, W, bias, out);
}

// Round 6
// 129.087 us; speedup vs baseline: 1.6471x; 1.0235x over previous
//
#include <hip/hip_runtime.h>
#include <math.h>

#define B_DIM 16
#define C_DIM 256
#define NV    40962
#define K_NEI 7
#define NPAIR (NV / 2)   // 20481
#define GRP   10241      // groups of 4 consecutive n per b (last group overlaps)

typedef float v2f __attribute__((ext_vector_type(2)));

// Kernel 1: channel-wise mean+max. Thread = (b, group of 4 consecutive n),
// loaded as two float2s (NV%4==2 -> float4 would be 8B-misaligned on odd c).
// Per c, a wave's two load instructions cover one contiguous 1KB span
// (vs 512B before) -> better HBM row locality. Last group per b overlaps the
// previous by 2 n; duplicate writes are bit-identical (same inputs, same
// order), so the race is benign and all threads run a uniform loop.
__global__ __launch_bounds__(256) void pool_kernel(const float* __restrict__ x,
                                                   float4* __restrict__ pool) {
    int t = blockIdx.x * 256 + threadIdx.x;
    if (t >= B_DIM * GRP) return;
    int b = t / GRP;
    int r = t - b * GRP;
    int n0 = 4 * r; if (n0 > NV - 4) n0 = NV - 4;   // 40958 for r=10240

    const float* xb = x + (size_t)b * C_DIM * NV + n0;

    float s0 = 0.f, s1 = 0.f, s2 = 0.f, s3 = 0.f;
    float m0 = -INFINITY, m1 = -INFINITY, m2 = -INFINITY, m3 = -INFINITY;
    #pragma unroll 16
    for (int c = 0; c < C_DIM; ++c) {
        const float* p = xb + (size_t)c * NV;
        v2f va = __builtin_nontemporal_load(reinterpret_cast<const v2f*>(p));
        v2f vb = __builtin_nontemporal_load(reinterpret_cast<const v2f*>(p + 2));
        s0 += va.x; s1 += va.y; s2 += vb.x; s3 += vb.y;
        m0 = fmaxf(m0, va.x); m1 = fmaxf(m1, va.y);
        m2 = fmaxf(m2, vb.x); m3 = fmaxf(m3, vb.y);
    }
    const float inv = 1.0f / (float)C_DIM;
    // pool layout [b][n] float2(avg,max); (b*NV + n0) even -> 16B-aligned float4s.
    size_t f4 = ((size_t)b * NV + n0) >> 1;
    pool[f4]     = make_float4(s0 * inv, m0, s1 * inv, m1);
    pool[f4 + 1] = make_float4(s2 * inv, m2, s3 * inv, m3);
}

// Kernel 2 (proven): transpose pool [b][n] -> poolT [n][b].
__global__ void transpose_kernel(const float2* __restrict__ pool,
                                 float2* __restrict__ poolT) {
    __shared__ float2 tile[64][17];
    int n0 = blockIdx.x * 64;
    int i  = threadIdx.x & 63;
    int bq = threadIdx.x >> 6;        // 0..3
    #pragma unroll
    for (int p = 0; p < 4; ++p) {
        int b = p * 4 + bq;
        if (n0 + i < NV)
            tile[i][b] = pool[(size_t)b * NV + n0 + i];
    }
    __syncthreads();
    int valid = NV - n0; if (valid > 64) valid = 64;
    int nf4 = valid * 8;
    float4* dst = reinterpret_cast<float4*>(poolT + (size_t)n0 * 16);
    for (int e = threadIdx.x; e < nf4; e += 256) {
        int e2 = e * 2;
        int n  = e2 >> 4;
        int b  = e2 & 15;
        float2 a0 = tile[n][b];
        float2 a1 = tile[n][b + 1];
        dst[e] = make_float4(a0.x, a0.y, a1.x, a1.y);
    }
}

// Kernel 3 (proven): 4 threads per vertex, 4 b each; full-line gathers.
__global__ void att4_kernel(const float2* __restrict__ poolT,
                            const int* __restrict__ idx,
                            const float* __restrict__ W,
                            const float* __restrict__ bias,
                            float* __restrict__ out) {
    int tid = threadIdx.x;
    int n   = blockIdx.x * 64 + (tid >> 2);
    int bq  = tid & 3;
    if (n >= NV) return;

    float w[2 * K_NEI];
    #pragma unroll
    for (int i = 0; i < 2 * K_NEI; ++i) w[i] = W[i];
    float bb = bias[0];

    float acc[4];
    #pragma unroll
    for (int r = 0; r < 4; ++r) acc[r] = bb;

    #pragma unroll
    for (int k = 0; k < K_NEI; ++k) {
        int j = idx[n * K_NEI + k];
        const float4* L = reinterpret_cast<const float4*>(poolT + (size_t)j * 16 + bq * 4);
        float4 v0 = L[0];
        float4 v1 = L[1];
        acc[0] = fmaf(w[2 * k + 1], v0.y, fmaf(w[2 * k], v0.x, acc[0]));
        acc[1] = fmaf(w[2 * k + 1], v0.w, fmaf(w[2 * k], v0.z, acc[1]));
        acc[2] = fmaf(w[2 * k + 1], v1.y, fmaf(w[2 * k], v1.x, acc[2]));
        acc[3] = fmaf(w[2 * k + 1], v1.w, fmaf(w[2 * k], v1.z, acc[3]));
    }
    #pragma unroll
    for (int r = 0; r < 4; ++r)
        out[(size_t)(bq * 4 + r) * NV + n] = 1.0f / (1.0f + expf(-acc[r]));
}

extern "C" void kernel_launch(void* const* d_in, const int* in_sizes, int n_in,
                              void* d_out, int out_size, void* d_ws, size_t ws_size,
                              hipStream_t stream) {
    const float* x     = (const float*)d_in[0];
    const int*   neigh = (const int*)  d_in[1];
    const float* W     = (const float*)d_in[2];
    const float* bias  = (const float*)d_in[3];
    float*       out   = (float*)d_out;

    const size_t POOL_BYTES = (size_t)B_DIM * NV * sizeof(float2); // 5.24 MB

    float4* pool4 = (float4*)d_ws;                        // [b][n] staging
    float2* poolT = (float2*)((char*)d_ws + POOL_BYTES);  // [n][b]

    int t1 = B_DIM * GRP;                 // 163,856
    pool_kernel<<<(t1 + 255) / 256, 256, 0, stream>>>(x, pool4);

    int ntile = (NV + 63) / 64;           // 641
    transpose_kernel<<<ntile, 256, 0, stream>>>((const float2*)d_ws, poolT);
    att4_kernel<<<ntile, 256, 0, stream>>>(poolT, neigh, W, bias, out);
}